// Round 7
// baseline (6047.217 us; speedup 1.0000x reference)
//
#include <hip/hip_runtime.h>

#define HID 64
#define TSTEPS 64
#define NTHREADS 512
#define ROWS_PB 128

typedef __attribute__((ext_vector_type(8))) _Float16 f16x8;
typedef __attribute__((ext_vector_type(2))) _Float16 f16x2;
typedef __attribute__((ext_vector_type(2))) __fp16  fp16x2raw;   // cvt_pkrtz return type
typedef __attribute__((ext_vector_type(4))) float f32x4;

__device__ __forceinline__ float fast_exp2(float x) { return __builtin_amdgcn_exp2f(x); }
__device__ __forceinline__ float fast_rcp(float x)  { return __builtin_amdgcn_rcpf(x); }
#define LOG2E 1.44269504088896341f

__device__ __forceinline__ float sigmoidf_(float x) { return fast_rcp(1.0f + fast_exp2(-LOG2E * x)); }

// clamp exp2 args so fused denominators never overflow (sigmoid/tanh already
// exactly saturated in fp32 at |arg|=26)
__device__ __forceinline__ float clampe(float x) { return fminf(fmaxf(x, -26.0f), 26.0f); }

// sigmoid(a) * tanh(b) with a single rcp:
//   A=e^-a, B=e^{2b};  sig(a)*tanh(b) = (B-1) / ((1+A)(1+B))
__device__ __forceinline__ float sigtanh(float a, float b) {
    float A = fast_exp2(clampe(-LOG2E * a));
    float B = fast_exp2(clampe(2.0f * LOG2E * b));
    float r = fast_rcp((1.0f + A) * (1.0f + B));
    return (B - 1.0f) * r;
}
// two sigmoids sharing one rcp: 1/da = db*r, 1/db = da*r with r=rcp(da*db)
__device__ __forceinline__ void sig2x(float a, float b, float& sa, float& sb) {
    float A  = fast_exp2(clampe(-LOG2E * a));
    float Bv = fast_exp2(clampe(-LOG2E * b));
    float da = 1.0f + A, db = 1.0f + Bv;
    float r = fast_rcp(da * db);
    sa = db * r; sb = da * r;
}

__device__ __forceinline__ f16x2 cvt_pk_f16(float a, float b) {
    fp16x2raw r = __builtin_amdgcn_cvt_pkrtz(a, b);
    return __builtin_bit_cast(f16x2, r);
}

__device__ __forceinline__ f32x4 MFMA16(f16x8 a, f16x8 b, f32x4 c) {
    return __builtin_amdgcn_mfma_f32_16x16x32_f16(a, b, c, 0, 0, 0);
}

// ---------------- LDS layout (bytes) ----------------
// steady state:
//   [0,     32768)  WA   : 16 tiles x 2 frags (f16 kc0, kc1) x 64 lanes x 16B
//   [32768, 36864)  EXT  : 16 tiles x 16 rows x 16B (f16 ext A-frag, g==0 lanes)
//   [36864, 36880)  ZERO : 16B zeros (broadcast for g>0 lanes)
//   [36880, 39972)  MOG  : fp32 tables
//   [40960, 73728)  XSEQ : [t=64][row=128] f32
// stem overlay: ping [0,34816), pong [34816,69632) -- dead before WA/EXT/MOG staging
#define OFF_WA    0
#define OFF_EXT   32768
#define OFF_ZERO  36864
#define OFF_MOGB  36880
#define OFF_XSEQ  40960
#define SMEM_TOTAL 73728

#define M0W 0
#define M2W 64
#define M4W 128
#define M1W 192
#define M1B 256
#define M3W 320
#define M3B 384
#define WPo 448
#define BPo 768

__global__ __launch_bounds__(NTHREADS, 2) void moglstm_mfma5(
    const float* __restrict__ x,
    const float* __restrict__ W1, const float* __restrict__ B1,
    const float* __restrict__ W2, const float* __restrict__ B2,
    const float* __restrict__ W3, const float* __restrict__ B3,
    const float* __restrict__ W4, const float* __restrict__ B4,
    const float* __restrict__ M0w, const float* __restrict__ M0b,
    const float* __restrict__ M1w, const float* __restrict__ M1b,
    const float* __restrict__ M2w, const float* __restrict__ M2b,
    const float* __restrict__ M3w, const float* __restrict__ M3b,
    const float* __restrict__ M4w, const float* __restrict__ M4b,
    const float* __restrict__ Wih, const float* __restrict__ Bih,
    const float* __restrict__ Whh, const float* __restrict__ Bhh,
    const float* __restrict__ Wp,  const float* __restrict__ Bp,
    float* __restrict__ out)
{
    __shared__ __align__(16) char smem[SMEM_TOTAL];
    f16x8* WAh   = (f16x8*)(smem + OFF_WA);
    float* mogf  = (float*)(smem + OFF_MOGB);
    float* sXseq = (float*)(smem + OFF_XSEQ);
    float* ping  = (float*)(smem);
    float* pong  = (float*)(smem + 34816);

    const int tid = threadIdx.x;
    const long rowbase = (long)blockIdx.x * ROWS_PB;

    // ================= MLP stem (4x Linear(64->64)+ReLU) =================
    for (int i = tid; i < ROWS_PB * 16; i += NTHREADS) {
        int r = i >> 4, c4 = i & 15;
        *(float4*)&ping[r * 68 + c4 * 4] = ((const float4*)x)[(rowbase + r) * 16 + c4];
    }
    __syncthreads();
    {
        const int sr = tid & 127;   // row
        const int sq = tid >> 7;    // quarter (wave-uniform) -> units sq*16..+15
        const float* Ws[4] = {W1, W2, W3, W4};
        const float* Bs[4] = {B1, B2, B3, B4};
        float rin[HID];
        #pragma unroll
        for (int L = 0; L < 4; ++L) {
            const float* SRC = (L & 1) ? pong : ping;
            float* DST       = (L & 1) ? ping : pong;
            #pragma unroll
            for (int k4 = 0; k4 < 16; ++k4) {
                float4 v = *(const float4*)&SRC[sr * 68 + k4 * 4];
                rin[4*k4+0] = v.x; rin[4*k4+1] = v.y; rin[4*k4+2] = v.z; rin[4*k4+3] = v.w;
            }
            __syncthreads();
            const float* W = Ws[L];
            const float* Bb = Bs[L];
            #pragma unroll
            for (int jj4 = 0; jj4 < 4; ++jj4) {
                float o[4];
                #pragma unroll
                for (int e = 0; e < 4; ++e) {
                    int j = sq * 16 + jj4 * 4 + e;
                    float a = Bb[j];
                    const float4* wr = (const float4*)(W + j * 64);  // wave-uniform -> s_load
                    #pragma unroll
                    for (int k4 = 0; k4 < 16; ++k4) {
                        float4 w = wr[k4];
                        a += w.x*rin[4*k4] + w.y*rin[4*k4+1] + w.z*rin[4*k4+2] + w.w*rin[4*k4+3];
                    }
                    o[e] = fmaxf(a, 0.0f);
                }
                *(float4*)&DST[sr * 68 + sq * 16 + jj4 * 4] = make_float4(o[0], o[1], o[2], o[3]);
            }
            __syncthreads();
        }
    }
    // final stem output in ping

    // ---- transpose stem output into XSEQ[t][row] (disjoint region) ----
    for (int i = tid; i < TSTEPS * ROWS_PB; i += NTHREADS) {
        int t = i >> 7, r = i & 127;
        sXseq[i] = ping[r * 68 + t];
    }
    __syncthreads();   // ping reads done; WA/EXT/MOG may overwrite overlay

    // ============ stage Whh f16 A-frags (frag order) ============
    // tile tt=(gi,u): rows = units gi*64 + u*16 + r ; lane(g,r) elem j -> k = kc*32+8g+j
    for (int i = tid; i < 2048; i += NTHREADS) {
        int ln = i & 63, kc = (i >> 6) & 1, tt = i >> 7;
        int gi = tt >> 2, u = tt & 3;
        int r = ln & 15, g = ln >> 4;
        const float* src = Whh + (gi * 64 + u * 16 + r) * 64 + kc * 32 + g * 8;
        f16x8 f;
        #pragma unroll
        for (int j = 0; j < 8; ++j) f[j] = (_Float16)src[j];
        WAh[(tt * 2 + kc) * 64 + ln] = f;
    }
    // compact ext frag: A[row r][k0..4] = {wihH, wihH, wihL, gbH, gbL} (f16 split)
    if (tid < 256) {
        int tt = tid >> 4, r = tid & 15;
        int G = (tt >> 2) * 64 + (tt & 3) * 16 + r;
        float wih = Wih[G];
        float gb  = Bih[G] + Bhh[G];
        _Float16 wh = (_Float16)wih;
        _Float16 wl = (_Float16)(wih - (float)wh);
        _Float16 gh = (_Float16)gb;
        _Float16 gl = (_Float16)(gb - (float)gh);
        f16x8 f = {wh, wh, wl, gh, gl, (_Float16)0.0f, (_Float16)0.0f, (_Float16)0.0f};
        *(f16x8*)(smem + OFF_EXT + tt * 256 + r * 16) = f;
    } else if (tid < 260) {
        ((float*)(smem + OFF_ZERO))[tid - 256] = 0.0f;
    }
    // mog/proj tables (pong region dead)
    if (tid >= 260 && tid < 324) {
        int k = tid - 260;
        mogf[M0W + k] = M0w[k];
        mogf[M2W + k] = M2w[k];
        mogf[M4W + k] = M4w[k];
        mogf[M1W + k] = M1w[k];
        mogf[M1B + k] = M1b[k];
        mogf[M3W + k] = M3w[k];
        mogf[M3B + k] = M3b[k];
    }
    for (int i = tid; i < 320; i += NTHREADS) mogf[WPo + i] = Wp[i];
    if (tid < 5) mogf[BPo + tid] = Bp[tid];
    __syncthreads();

    // ===================== mogrifier-LSTM recurrence =====================
    const int lane = tid & 63;
    const int wv   = tid >> 6;       // wave -> rows wv*16..+15
    const int g_   = lane >> 4;      // 0..3
    const int n    = lane & 15;      // batchrow within wave (A-row / D-col)
    const int myrow = wv * 16 + n;

    const char* extb    = smem + ((g_ == 0) ? (OFF_EXT + n * 16) : OFF_ZERO);
    const int   extstep = (g_ == 0) ? 256 : 0;
    const float m0b_s = M0b[0], m2b_s = M2b[0], m4b_s = M4b[0];
    const bool glow  = (g_ < 2);
    const bool geven = ((g_ & 1) == 0);

    // hB[kc*8+j] = h[unit kc*32 + 8g_ + j] of row n (fp32, B-operand order)
    float hB[16];
    f32x4 cst[4];
    #pragma unroll
    for (int i = 0; i < 16; ++i) hB[i] = 0.0f;
    #pragma unroll
    for (int u = 0; u < 4; ++u) cst[u] = (f32x4){0.0f, 0.0f, 0.0f, 0.0f};

#define MOG_DOT(MOFF, BIAS)                                                   \
    {                                                                         \
        float4 w0 = *(const float4*)&mogf[(MOFF) + g_ * 8];                   \
        float4 w1 = *(const float4*)&mogf[(MOFF) + g_ * 8 + 4];               \
        float4 w2 = *(const float4*)&mogf[(MOFF) + 32 + g_ * 8];              \
        float4 w3 = *(const float4*)&mogf[(MOFF) + 32 + g_ * 8 + 4];          \
        float p = w0.x*hB[0] + w0.y*hB[1] + w0.z*hB[2] + w0.w*hB[3]           \
                + w1.x*hB[4] + w1.y*hB[5] + w1.z*hB[6] + w1.w*hB[7]           \
                + w2.x*hB[8] + w2.y*hB[9] + w2.z*hB[10] + w2.w*hB[11]         \
                + w3.x*hB[12] + w3.y*hB[13] + w3.z*hB[14] + w3.w*hB[15];      \
        p += __shfl_xor(p, 16);                                               \
        p += __shfl_xor(p, 32);                                               \
        xt *= 2.0f * sigmoidf_(p + (BIAS));                                   \
    }

#define MOG_SCALE(WOFF, BOFF)                                                 \
    {                                                                         \
        _Pragma("unroll")                                                     \
        for (int kc = 0; kc < 2; ++kc) {                                      \
            _Pragma("unroll")                                                 \
            for (int q = 0; q < 2; ++q) {                                     \
                float4 w4 = *(const float4*)&mogf[(WOFF) + kc*32 + g_*8 + q*4]; \
                float4 b4 = *(const float4*)&mogf[(BOFF) + kc*32 + g_*8 + q*4]; \
                int bse = kc * 8 + q * 4;                                     \
                float sa, sb;                                                 \
                sig2x(xt * w4.x + b4.x, xt * w4.y + b4.y, sa, sb);            \
                hB[bse+0] *= 2.0f * sa;                                       \
                hB[bse+1] *= 2.0f * sb;                                       \
                sig2x(xt * w4.z + b4.z, xt * w4.w + b4.w, sa, sb);            \
                hB[bse+2] *= 2.0f * sa;                                       \
                hB[bse+3] *= 2.0f * sb;                                       \
            }                                                                 \
        }                                                                     \
    }

    #pragma unroll 1
    for (int t = 0; t < TSTEPS; ++t) {
        float xt = sXseq[t * 128 + myrow];   // broadcast ds_read_b32

        // ---- mogrifier (fp32) ----
        MOG_DOT(M0W, m0b_s)
        MOG_SCALE(M1W, M1B)
        MOG_DOT(M2W, m2b_s)
        MOG_SCALE(M3W, M3B)
        MOG_DOT(M4W, m4b_s)

        // ---- B-frags: h -> split fp16 (hi + residual) ----
        union uf8 { f16x8 v; f16x2 h2[4]; };
        uf8 bhi0, bhi1, blo0, blo1;
        #pragma unroll
        for (int kc = 0; kc < 2; ++kc) {
            #pragma unroll
            for (int jp = 0; jp < 4; ++jp) {
                float a = hB[kc * 8 + 2 * jp], b = hB[kc * 8 + 2 * jp + 1];
                f16x2 hi2 = cvt_pk_f16(a, b);
                f16x2 lo2 = cvt_pk_f16(a - (float)hi2[0], b - (float)hi2[1]);
                if (kc == 0) { bhi0.h2[jp] = hi2; blo0.h2[jp] = lo2; }
                else         { bhi1.h2[jp] = hi2; blo1.h2[jp] = lo2; }
            }
        }
        // ext B: k-slots {xtH, xtL, xtH, 1, 1, 0, 0, 0}
        f16x8 bext;
        {
            _Float16 xh = (_Float16)xt;
            _Float16 xl = (_Float16)(xt - (float)xh);
            bext = (f16x8){xh, xl, xh, (_Float16)1.0f, (_Float16)1.0f,
                           (_Float16)0.0f, (_Float16)0.0f, (_Float16)0.0f};
        }

        auto gate_tile = [&](int tt) -> f32x4 {
            f16x8 w0 = WAh[(tt * 2 + 0) * 64 + lane];
            f16x8 w1 = WAh[(tt * 2 + 1) * 64 + lane];
            f16x8 we = *(const f16x8*)(extb + tt * extstep);
            f32x4 d = {0.0f, 0.0f, 0.0f, 0.0f};
            d = MFMA16(we, bext, d);
            d = MFMA16(w0, bhi0.v, d);
            d = MFMA16(w1, bhi1.v, d);
            d = MFMA16(w0, blo0.v, d);
            d = MFMA16(w1, blo1.v, d);
            return d;
        };

        // ---- half 1: gates i (tiles 0-3) and g (tiles 8-11) -> p1 = sig(i)*tanh(g) ----
        f32x4 p1[4];
        {
            f32x4 acci[4], accg[4];
            #pragma unroll
            for (int u = 0; u < 4; ++u) { acci[u] = gate_tile(u); accg[u] = gate_tile(8 + u); }
            #pragma unroll
            for (int u = 0; u < 4; ++u)
                #pragma unroll
                for (int e = 0; e < 4; ++e)
                    p1[u][e] = sigtanh(acci[u][e], accg[u][e]);
        }

        // ---- half 2: gates f (tiles 4-7) and o (tiles 12-15) -> c, h ----
        float hn[4][4];
        {
            f32x4 accf[4], acco[4];
            #pragma unroll
            for (int u = 0; u < 4; ++u) { accf[u] = gate_tile(4 + u); acco[u] = gate_tile(12 + u); }
            #pragma unroll
            for (int u = 0; u < 4; ++u) {
                float s0, s1, s2, s3;
                sig2x(accf[u][0], accf[u][1], s0, s1);
                sig2x(accf[u][2], accf[u][3], s2, s3);
                float c0 = s0 * cst[u][0] + p1[u][0];
                float c1 = s1 * cst[u][1] + p1[u][1];
                float c2 = s2 * cst[u][2] + p1[u][2];
                float c3 = s3 * cst[u][3] + p1[u][3];
                cst[u][0] = c0; cst[u][1] = c1; cst[u][2] = c2; cst[u][3] = c3;
                hn[u][0] = sigtanh(acco[u][0], c0);
                hn[u][1] = sigtanh(acco[u][1], c1);
                hn[u][2] = sigtanh(acco[u][2], c2);
                hn[u][3] = sigtanh(acco[u][3], c3);
            }
        }

        // ---- redistribute hn (unit 16u+4g+e, row n) -> hB (unit kc*32+8g+j) ----
        #pragma unroll
        for (int up = 0; up < 2; ++up) {
            #pragma unroll
            for (int e = 0; e < 4; ++e) {
                float send = glow ? hn[2 * up + 1][e] : hn[2 * up][e];
                float got = __shfl_xor(send, 32);
                hn[2 * up + 1][e] = glow ? got : hn[2 * up + 1][e];
                hn[2 * up][e]     = glow ? hn[2 * up][e] : got;
            }
        }
        #pragma unroll
        for (int up = 0; up < 2; ++up) {
            #pragma unroll
            for (int e = 0; e < 4; ++e) {
                float send = geven ? hn[2 * up + 1][e] : hn[2 * up][e];
                float got = __shfl_xor(send, 16);
                hn[2 * up + 1][e] = geven ? got : hn[2 * up + 1][e];
                hn[2 * up][e]     = geven ? hn[2 * up][e] : got;
            }
        }
        #pragma unroll
        for (int kc = 0; kc < 2; ++kc)
            #pragma unroll
            for (int j = 0; j < 8; ++j)
                hB[kc * 8 + j] = hn[2 * kc + (j >> 2)][j & 3];
    }

    // ===================== projection: out = h @ Wp^T + Bp =====================
    #pragma unroll
    for (int p = 0; p < 5; ++p) {
        float ap = 0.0f;
        #pragma unroll
        for (int kc = 0; kc < 2; ++kc) {
            #pragma unroll
            for (int q = 0; q < 2; ++q) {
                float4 w = *(const float4*)&mogf[WPo + p * 64 + kc * 32 + g_ * 8 + q * 4];
                ap += w.x * hB[kc * 8 + q * 4 + 0] + w.y * hB[kc * 8 + q * 4 + 1]
                    + w.z * hB[kc * 8 + q * 4 + 2] + w.w * hB[kc * 8 + q * 4 + 3];
            }
        }
        ap += __shfl_xor(ap, 16);
        ap += __shfl_xor(ap, 32);
        if (g_ == 0)
            out[(rowbase + myrow) * 5 + p] = ap + mogf[BPo + p];
    }
}

extern "C" void kernel_launch(void* const* d_in, const int* in_sizes, int n_in,
                              void* d_out, int out_size, void* d_ws, size_t ws_size,
                              hipStream_t stream) {
    const float* x   = (const float*)d_in[0];
    const float* W1  = (const float*)d_in[1];
    const float* B1  = (const float*)d_in[2];
    const float* W2  = (const float*)d_in[3];
    const float* B2  = (const float*)d_in[4];
    const float* W3  = (const float*)d_in[5];
    const float* B3  = (const float*)d_in[6];
    const float* W4  = (const float*)d_in[7];
    const float* B4  = (const float*)d_in[8];
    const float* M0w = (const float*)d_in[9];
    const float* M0b = (const float*)d_in[10];
    const float* M1w = (const float*)d_in[11];
    const float* M1b = (const float*)d_in[12];
    const float* M2w = (const float*)d_in[13];
    const float* M2b = (const float*)d_in[14];
    const float* M3w = (const float*)d_in[15];
    const float* M3b = (const float*)d_in[16];
    const float* M4w = (const float*)d_in[17];
    const float* M4b = (const float*)d_in[18];
    const float* Wih = (const float*)d_in[19];
    const float* Bih = (const float*)d_in[20];
    const float* Whh = (const float*)d_in[21];
    const float* Bhh = (const float*)d_in[22];
    const float* Wp  = (const float*)d_in[23];
    const float* Bp  = (const float*)d_in[24];

    int B = in_sizes[0] / HID;          // 262144
    int nblocks = B / ROWS_PB;          // 2048

    hipLaunchKernelGGL(moglstm_mfma5, dim3(nblocks), dim3(NTHREADS), 0, stream,
                       x, W1, B1, W2, B2, W3, B3, W4, B4,
                       M0w, M0b, M1w, M1b, M2w, M2b, M3w, M3b, M4w, M4b,
                       Wih, Bih, Whh, Bhh, Wp, Bp, (float*)d_out);
}

// Round 8
// 2946.544 us; speedup vs baseline: 2.0523x; 2.0523x over previous
//
#include <hip/hip_runtime.h>

#define HID 64
#define TSTEPS 64
#define NTHREADS 512
#define ROWS_PB 128

typedef __attribute__((ext_vector_type(8))) short bf16x8;
typedef __attribute__((ext_vector_type(4))) float f32x4;

__device__ __forceinline__ float fast_exp2(float x) { return __builtin_amdgcn_exp2f(x); }
__device__ __forceinline__ float fast_rcp(float x)  { return __builtin_amdgcn_rcpf(x); }
#define LOG2E 1.44269504088896341f
__device__ __forceinline__ float sigmoidf_(float x) { return fast_rcp(1.0f + fast_exp2(-LOG2E * x)); }
__device__ __forceinline__ float tanhf_(float x)    { return 1.0f - 2.0f * fast_rcp(1.0f + fast_exp2(2.0f * LOG2E * x)); }

__device__ __forceinline__ unsigned short f2bf(float f) {   // RNE fp32->bf16
    unsigned u = __float_as_uint(f);
    u = u + 0x7fffu + ((u >> 16) & 1u);
    return (unsigned short)(u >> 16);
}
__device__ __forceinline__ float bfh(unsigned short h) { return __uint_as_float(((unsigned)h) << 16); }
__device__ __forceinline__ unsigned cvt_pk_bf16(float a, float b) {  // low16=bf(a), high16=bf(b)
    unsigned r;
    asm("v_cvt_pk_bf16_f32 %0, %1, %2" : "=v"(r) : "v"(a), "v"(b));
    return r;
}

// ---------------- LDS layout (bytes) ----------------
// steady state:
//   [0,     32768)  WA   : 16 tiles x 2 frags (bf16-hi kc0, kc1) x 64 lanes x 16B
//   [32768, 36864)  EXT  : 16 tiles x 16 rows x 16B (bias+Wih A-frag, g==0 lanes)
//   [36864, 36880)  ZERO : 16B zeros (broadcast for g>0 lanes)
//   [36880, 39972)  MOG  : fp32 tables (float offsets below)
//   [40960, 73728)  XSEQ : [t=64][row=128] f32
// stem overlay: ping [0,34816), pong [34816,69632).
//   ping live until transpose done; pong dead after stem L4.
//   WA/EXT/ZERO/MOG staged only AFTER the post-transpose barrier.
#define OFF_WA    0
#define OFF_EXT   32768
#define OFF_ZERO  36864
#define OFF_MOGB  36880
#define OFF_XSEQ  40960
#define SMEM_TOTAL 73728

#define M0W 0
#define M2W 64
#define M4W 128
#define M1W 192
#define M1B 256
#define M3W 320
#define M3B 384
#define WPo 448
#define BPo 768

__global__ __launch_bounds__(NTHREADS, 2) void moglstm_mfma6(
    const float* __restrict__ x,
    const float* __restrict__ W1, const float* __restrict__ B1,
    const float* __restrict__ W2, const float* __restrict__ B2,
    const float* __restrict__ W3, const float* __restrict__ B3,
    const float* __restrict__ W4, const float* __restrict__ B4,
    const float* __restrict__ M0w, const float* __restrict__ M0b,
    const float* __restrict__ M1w, const float* __restrict__ M1b,
    const float* __restrict__ M2w, const float* __restrict__ M2b,
    const float* __restrict__ M3w, const float* __restrict__ M3b,
    const float* __restrict__ M4w, const float* __restrict__ M4b,
    const float* __restrict__ Wih, const float* __restrict__ Bih,
    const float* __restrict__ Whh, const float* __restrict__ Bhh,
    const float* __restrict__ Wp,  const float* __restrict__ Bp,
    float* __restrict__ out)
{
    __shared__ __align__(16) char smem[SMEM_TOTAL];
    bf16x8* WA    = (bf16x8*)(smem + OFF_WA);
    float*  mogf  = (float*)(smem + OFF_MOGB);
    float*  sXseq = (float*)(smem + OFF_XSEQ);
    float*  ping  = (float*)(smem);
    float*  pong  = (float*)(smem + 34816);

    const int tid = threadIdx.x;
    const long rowbase = (long)blockIdx.x * ROWS_PB;

    // ================= MLP stem (4x Linear(64->64)+ReLU) =================
    for (int i = tid; i < ROWS_PB * 16; i += NTHREADS) {
        int r = i >> 4, c4 = i & 15;
        *(float4*)&ping[r * 68 + c4 * 4] = ((const float4*)x)[(rowbase + r) * 16 + c4];
    }
    __syncthreads();
    {
        const int sr = tid & 127;   // row
        const int sq = tid >> 7;    // quarter (wave-uniform) -> units sq*16..+15
        const float* Ws[4] = {W1, W2, W3, W4};
        const float* Bs[4] = {B1, B2, B3, B4};
        float rin[HID];
        #pragma unroll
        for (int L = 0; L < 4; ++L) {
            const float* SRC = (L & 1) ? pong : ping;
            float* DST       = (L & 1) ? ping : pong;
            #pragma unroll
            for (int k4 = 0; k4 < 16; ++k4) {
                float4 v = *(const float4*)&SRC[sr * 68 + k4 * 4];
                rin[4*k4+0] = v.x; rin[4*k4+1] = v.y; rin[4*k4+2] = v.z; rin[4*k4+3] = v.w;
            }
            __syncthreads();
            const float* W = Ws[L];
            const float* Bb = Bs[L];
            #pragma unroll
            for (int jj4 = 0; jj4 < 4; ++jj4) {
                float o[4];
                #pragma unroll
                for (int e = 0; e < 4; ++e) {
                    int j = sq * 16 + jj4 * 4 + e;
                    float a = Bb[j];
                    const float4* wr = (const float4*)(W + j * 64);  // wave-uniform -> s_load
                    #pragma unroll
                    for (int k4 = 0; k4 < 16; ++k4) {
                        float4 w = wr[k4];
                        a += w.x*rin[4*k4] + w.y*rin[4*k4+1] + w.z*rin[4*k4+2] + w.w*rin[4*k4+3];
                    }
                    o[e] = fmaxf(a, 0.0f);
                }
                *(float4*)&DST[sr * 68 + sq * 16 + jj4 * 4] = make_float4(o[0], o[1], o[2], o[3]);
            }
            __syncthreads();
        }
    }
    // final stem output in ping

    // ---- transpose stem output into XSEQ[t][row] (over dead pong + fresh tail) ----
    for (int i = tid; i < TSTEPS * ROWS_PB; i += NTHREADS) {
        int t = i >> 7, r = i & 127;
        sXseq[i] = ping[r * 68 + t];
    }
    __syncthreads();   // ping reads done; WA/EXT/ZERO/MOG may overwrite overlays

    // ============ stage Whh bf16-hi A-frags (frag order) ============
    // tile tt=(gi,u): rows = units gi*64 + u*16 + r ; lane(g,r) elem j -> k = kc*32+8g+j
    for (int i = tid; i < 2048; i += NTHREADS) {
        int ln = i & 63, kc = (i >> 6) & 1, tt = i >> 7;
        int gi = tt >> 2, u = tt & 3;
        int r = ln & 15, g = ln >> 4;
        const float* src = Whh + (gi * 64 + u * 16 + r) * 64 + kc * 32 + g * 8;
        union { bf16x8 v; unsigned short s[8]; } f;
        #pragma unroll
        for (int j = 0; j < 8; ++j) f.s[j] = f2bf(src[j]);
        WA[(tt * 2 + kc) * 64 + ln] = f.v;
    }
    // compact ext frag: A[row r][k0..4] = {wih_hi, wih_hi, wih_lo, gb_hi, gb_lo}
    if (tid < 256) {
        int tt = tid >> 4, r = tid & 15;
        int G = (tt >> 2) * 64 + (tt & 3) * 16 + r;
        float wih = Wih[G];
        float gb  = Bih[G] + Bhh[G];
        unsigned short wh = f2bf(wih);
        unsigned short wl = f2bf(wih - bfh(wh));
        unsigned short gh = f2bf(gb);
        unsigned short gl = f2bf(gb - bfh(gh));
        union { bf16x8 v; unsigned u[4]; } f;
        f.u[0] = (unsigned)wh | ((unsigned)wh << 16);
        f.u[1] = (unsigned)wl | ((unsigned)gh << 16);
        f.u[2] = (unsigned)gl;
        f.u[3] = 0u;
        *(bf16x8*)(smem + OFF_EXT + tt * 256 + r * 16) = f.v;
    } else if (tid < 260) {
        ((float*)(smem + OFF_ZERO))[tid - 256] = 0.0f;
    }
    // mog/proj tables (pong region dead)
    if (tid >= 260 && tid < 324) {
        int k = tid - 260;
        mogf[M0W + k] = M0w[k];
        mogf[M2W + k] = M2w[k];
        mogf[M4W + k] = M4w[k];
        mogf[M1W + k] = M1w[k];
        mogf[M1B + k] = M1b[k];
        mogf[M3W + k] = M3w[k];
        mogf[M3B + k] = M3b[k];
    }
    for (int i = tid; i < 320; i += NTHREADS) mogf[WPo + i] = Wp[i];
    if (tid < 5) mogf[BPo + tid] = Bp[tid];
    __syncthreads();

    // ===================== mogrifier-LSTM recurrence =====================
    const int lane = tid & 63;
    const int wv   = tid >> 6;       // wave -> rows wv*16..+15
    const int g_   = lane >> 4;      // 0..3
    const int n    = lane & 15;      // batchrow within wave (A-row / D-col)
    const int myrow = wv * 16 + n;

    const char* extb    = smem + ((g_ == 0) ? (OFF_EXT + n * 16) : OFF_ZERO);
    const int   extstep = (g_ == 0) ? 256 : 0;
    const float m0b_s = M0b[0], m2b_s = M2b[0], m4b_s = M4b[0];
    const bool glow  = (g_ < 2);
    const bool geven = ((g_ & 1) == 0);

    // hB[kc*8+j] = h[unit kc*32 + 8g_ + j] of row n (fp32, B-operand order)
    float hB[16];
    f32x4 cst[4];
    #pragma unroll
    for (int i = 0; i < 16; ++i) hB[i] = 0.0f;
    #pragma unroll
    for (int u = 0; u < 4; ++u) cst[u] = (f32x4){0.0f, 0.0f, 0.0f, 0.0f};

#define MOG_DOT(MOFF, BIAS)                                                   \
    {                                                                         \
        float4 w0 = *(const float4*)&mogf[(MOFF) + g_ * 8];                   \
        float4 w1 = *(const float4*)&mogf[(MOFF) + g_ * 8 + 4];               \
        float4 w2 = *(const float4*)&mogf[(MOFF) + 32 + g_ * 8];              \
        float4 w3 = *(const float4*)&mogf[(MOFF) + 32 + g_ * 8 + 4];          \
        float p = w0.x*hB[0] + w0.y*hB[1] + w0.z*hB[2] + w0.w*hB[3]           \
                + w1.x*hB[4] + w1.y*hB[5] + w1.z*hB[6] + w1.w*hB[7]           \
                + w2.x*hB[8] + w2.y*hB[9] + w2.z*hB[10] + w2.w*hB[11]         \
                + w3.x*hB[12] + w3.y*hB[13] + w3.z*hB[14] + w3.w*hB[15];      \
        p += __shfl_xor(p, 16);                                               \
        p += __shfl_xor(p, 32);                                               \
        xt *= 2.0f * sigmoidf_(p + (BIAS));                                   \
    }

#define MOG_SCALE(WOFF, BOFF)                                                 \
    {                                                                         \
        _Pragma("unroll")                                                     \
        for (int kc = 0; kc < 2; ++kc) {                                      \
            _Pragma("unroll")                                                 \
            for (int q = 0; q < 2; ++q) {                                     \
                float4 w4 = *(const float4*)&mogf[(WOFF) + kc*32 + g_*8 + q*4]; \
                float4 b4 = *(const float4*)&mogf[(BOFF) + kc*32 + g_*8 + q*4]; \
                int bse = kc * 8 + q * 4;                                     \
                hB[bse+0] *= 2.0f * sigmoidf_(xt * w4.x + b4.x);              \
                hB[bse+1] *= 2.0f * sigmoidf_(xt * w4.y + b4.y);              \
                hB[bse+2] *= 2.0f * sigmoidf_(xt * w4.z + b4.z);              \
                hB[bse+3] *= 2.0f * sigmoidf_(xt * w4.w + b4.w);              \
            }                                                                 \
        }                                                                     \
    }

    #pragma unroll 1
    for (int t = 0; t < TSTEPS; ++t) {
        float xt = sXseq[t * 128 + myrow];   // broadcast ds_read_b32

        // ---- mogrifier (fp32) ----
        MOG_DOT(M0W, m0b_s)
        MOG_SCALE(M1W, M1B)
        MOG_DOT(M2W, m2b_s)
        MOG_SCALE(M3W, M3B)
        MOG_DOT(M4W, m4b_s)

        // ---- B-frags: h -> split bf16 ----
        union uf8 { bf16x8 v; unsigned u[4]; };
        uf8 bhi0, bhi1, blo0, blo1, bext;
        #pragma unroll
        for (int kc = 0; kc < 2; ++kc) {
            #pragma unroll
            for (int jp = 0; jp < 4; ++jp) {
                float a = hB[kc * 8 + 2 * jp], b = hB[kc * 8 + 2 * jp + 1];
                unsigned hi = cvt_pk_bf16(a, b);
                float ah = __uint_as_float(hi << 16);
                float bh = __uint_as_float(hi & 0xffff0000u);
                unsigned lo = cvt_pk_bf16(a - ah, b - bh);
                if (kc == 0) { bhi0.u[jp] = hi; blo0.u[jp] = lo; }
                else         { bhi1.u[jp] = hi; blo1.u[jp] = lo; }
            }
        }
        {   // ext B: k-slots {xt_hi, xt_lo, xt_hi, 1, 1, 0, 0, 0}
            unsigned xh = cvt_pk_bf16(xt, xt) & 0xffffu;
            float xl = xt - bfh((unsigned short)xh);
            unsigned xlp = cvt_pk_bf16(xl, xl) & 0xffffu;
            bext.u[0] = xh | (xlp << 16);
            bext.u[1] = xh | (0x3F80u << 16);
            bext.u[2] = 0x3F80u;
            bext.u[3] = 0u;
        }

        // gates = Whh_bf16 @ (h_hi + h_lo) + xt*Wih + b  (5 MFMAs per tile)
        auto gate_tile = [&](int tt) -> f32x4 {
            bf16x8 whi0 = WA[(tt * 2 + 0) * 64 + lane];
            bf16x8 whi1 = WA[(tt * 2 + 1) * 64 + lane];
            bf16x8 wext = *(const bf16x8*)(extb + tt * extstep);
            f32x4 d = {0.0f, 0.0f, 0.0f, 0.0f};
            d = __builtin_amdgcn_mfma_f32_16x16x32_bf16(wext, bext.v, d, 0, 0, 0);
            d = __builtin_amdgcn_mfma_f32_16x16x32_bf16(whi0, bhi0.v, d, 0, 0, 0);
            d = __builtin_amdgcn_mfma_f32_16x16x32_bf16(whi1, bhi1.v, d, 0, 0, 0);
            d = __builtin_amdgcn_mfma_f32_16x16x32_bf16(whi0, blo0.v, d, 0, 0, 0);
            d = __builtin_amdgcn_mfma_f32_16x16x32_bf16(whi1, blo1.v, d, 0, 0, 0);
            return d;
        };

        // ---- half 1: gates i (tiles 0-3) and g (tiles 8-11) -> p1 ----
        f32x4 p1[4];
        {
            f32x4 acci[4], accg[4];
            #pragma unroll
            for (int u = 0; u < 4; ++u) { acci[u] = gate_tile(u); accg[u] = gate_tile(8 + u); }
            #pragma unroll
            for (int u = 0; u < 4; ++u)
                #pragma unroll
                for (int e = 0; e < 4; ++e)
                    p1[u][e] = sigmoidf_(acci[u][e]) * tanhf_(accg[u][e]);
        }

        // ---- half 2: gates f (tiles 4-7) and o (tiles 12-15) -> c, h ----
        float hn[4][4];
        {
            f32x4 accf[4], acco[4];
            #pragma unroll
            for (int u = 0; u < 4; ++u) { accf[u] = gate_tile(4 + u); acco[u] = gate_tile(12 + u); }
            #pragma unroll
            for (int u = 0; u < 4; ++u)
                #pragma unroll
                for (int e = 0; e < 4; ++e) {
                    float cc = sigmoidf_(accf[u][e]) * cst[u][e] + p1[u][e];
                    cst[u][e] = cc;
                    hn[u][e] = sigmoidf_(acco[u][e]) * tanhf_(cc);
                }
        }

        // ---- redistribute hn (unit 16u+4g+e, row n) -> hB (unit kc*32+8g+j) ----
        #pragma unroll
        for (int up = 0; up < 2; ++up) {
            #pragma unroll
            for (int e = 0; e < 4; ++e) {
                float send = glow ? hn[2 * up + 1][e] : hn[2 * up][e];
                float got = __shfl_xor(send, 32);
                hn[2 * up + 1][e] = glow ? got : hn[2 * up + 1][e];
                hn[2 * up][e]     = glow ? hn[2 * up][e] : got;
            }
        }
        #pragma unroll
        for (int up = 0; up < 2; ++up) {
            #pragma unroll
            for (int e = 0; e < 4; ++e) {
                float send = geven ? hn[2 * up + 1][e] : hn[2 * up][e];
                float got = __shfl_xor(send, 16);
                hn[2 * up + 1][e] = geven ? got : hn[2 * up + 1][e];
                hn[2 * up][e]     = geven ? hn[2 * up][e] : got;
            }
        }
        #pragma unroll
        for (int kc = 0; kc < 2; ++kc)
            #pragma unroll
            for (int j = 0; j < 8; ++j)
                hB[kc * 8 + j] = hn[2 * kc + (j >> 2)][j & 3];
    }

    // ===================== projection: out = h @ Wp^T + Bp =====================
    #pragma unroll
    for (int p = 0; p < 5; ++p) {
        float ap = 0.0f;
        #pragma unroll
        for (int kc = 0; kc < 2; ++kc) {
            #pragma unroll
            for (int q = 0; q < 2; ++q) {
                float4 w = *(const float4*)&mogf[WPo + p * 64 + kc * 32 + g_ * 8 + q * 4];
                ap += w.x * hB[kc * 8 + q * 4 + 0] + w.y * hB[kc * 8 + q * 4 + 1]
                    + w.z * hB[kc * 8 + q * 4 + 2] + w.w * hB[kc * 8 + q * 4 + 3];
            }
        }
        ap += __shfl_xor(ap, 16);
        ap += __shfl_xor(ap, 32);
        if (g_ == 0)
            out[(rowbase + myrow) * 5 + p] = ap + mogf[BPo + p];
    }
}

extern "C" void kernel_launch(void* const* d_in, const int* in_sizes, int n_in,
                              void* d_out, int out_size, void* d_ws, size_t ws_size,
                              hipStream_t stream) {
    const float* x   = (const float*)d_in[0];
    const float* W1  = (const float*)d_in[1];
    const float* B1  = (const float*)d_in[2];
    const float* W2  = (const float*)d_in[3];
    const float* B2  = (const float*)d_in[4];
    const float* W3  = (const float*)d_in[5];
    const float* B3  = (const float*)d_in[6];
    const float* W4  = (const float*)d_in[7];
    const float* B4  = (const float*)d_in[8];
    const float* M0w = (const float*)d_in[9];
    const float* M0b = (const float*)d_in[10];
    const float* M1w = (const float*)d_in[11];
    const float* M1b = (const float*)d_in[12];
    const float* M2w = (const float*)d_in[13];
    const float* M2b = (const float*)d_in[14];
    const float* M3w = (const float*)d_in[15];
    const float* M3b = (const float*)d_in[16];
    const float* M4w = (const float*)d_in[17];
    const float* M4b = (const float*)d_in[18];
    const float* Wih = (const float*)d_in[19];
    const float* Bih = (const float*)d_in[20];
    const float* Whh = (const float*)d_in[21];
    const float* Bhh = (const float*)d_in[22];
    const float* Wp  = (const float*)d_in[23];
    const float* Bp  = (const float*)d_in[24];

    int B = in_sizes[0] / HID;          // 262144
    int nblocks = B / ROWS_PB;          // 2048

    hipLaunchKernelGGL(moglstm_mfma6, dim3(nblocks), dim3(NTHREADS), 0, stream,
                       x, W1, B1, W2, B2, W3, B3, W4, B4,
                       M0w, M0b, M1w, M1b, M2w, M2b, M3w, M3b, M4w, M4b,
                       Wih, Bih, Whh, Bhh, Wp, Bp, (float*)d_out);
}